// Round 20
// baseline (117.600 us; speedup 1.0000x reference)
//
#include <hip/hip_runtime.h>
#include <stdint.h>

// Problem constants
#define NB 2
#define NS 2048
#define ND 1024
#define NH 16
#define NHD 64
#define SCALE_QL2 0.1803368801111244f  // (1/sqrt(64)) * log2(e): attention runs in exp2 domain

typedef __attribute__((ext_vector_type(8))) short bf16x8;
typedef __attribute__((ext_vector_type(4))) float f32x4;
typedef __attribute__((ext_vector_type(16))) float f32x16;
typedef __attribute__((ext_vector_type(8))) unsigned short u16x8;

__device__ __forceinline__ unsigned short f2bf(float f) {
  union { float f; unsigned u; } v; v.f = f;
  unsigned r = v.u + 0x7FFFu + ((v.u >> 16) & 1u);
  return (unsigned short)(r >> 16);
}

__device__ __forceinline__ float bf2f(unsigned short u) {
  union { unsigned u; float f; } v; v.u = ((unsigned)u) << 16;
  return v.f;
}

__device__ __forceinline__ float fexp2(float x) { return __builtin_amdgcn_exp2f(x); }

// 3-input max, single VALU op (gfx9+); T17
__device__ __forceinline__ float max3f(float a, float b, float c) {
  float r;
  asm("v_max3_f32 %0, %1, %2, %3" : "=v"(r) : "v"(a), "v"(b), "v"(c));
  return r;
}

// pack 2 f32 -> 1 u32 of 2 bf16 (lo = a, hi = b), RNE
__device__ __forceinline__ unsigned cvtpk(float a, float b) {
  unsigned r;
  asm("v_cvt_pk_bf16_f32 %0, %1, %2" : "=v"(r) : "v"(a), "v"(b));
  return r;
}

// cross-half exchange: a' = [a_lo32lanes, b_lo32lanes], b' = [a_hi32lanes, b_hi32lanes]
__device__ __forceinline__ void plswap(unsigned& a, unsigned& b) {
  asm("v_permlane32_swap_b32 %0, %1" : "+v"(a), "+v"(b));
}

// async global->LDS, 16B per lane. Dest must be wave-uniform base (HW adds lane*16).
__device__ __forceinline__ void gload16(const void* g, void* l) {
  __builtin_amdgcn_global_load_lds(
      (const __attribute__((address_space(1))) unsigned int*)g,
      (__attribute__((address_space(3))) unsigned int*)l, 16, 0, 0);
}

// ---------------- merged prep kernel (cvt_x + both weight transposes) ----------------
__global__ void prep(const float* __restrict__ x, unsigned short* __restrict__ xb,
                     const float* __restrict__ W_qkv, unsigned short* __restrict__ WqkvT,
                     const float* __restrict__ W_proj, unsigned short* __restrict__ WprojT) {
  int bid = blockIdx.x;
  if (bid < 2048) {
    int i = bid * 256 + threadIdx.x;
    const float4* p = (const float4*)x + (size_t)i * 2;
    float4 a = p[0], b = p[1];
    u16x8 o;
    o[0] = f2bf(a.x); o[1] = f2bf(a.y); o[2] = f2bf(a.z); o[3] = f2bf(a.w);
    o[4] = f2bf(b.x); o[5] = f2bf(b.y); o[6] = f2bf(b.z); o[7] = f2bf(b.w);
    *((u16x8*)xb + i) = o;
    return;
  }
  const float* W; unsigned short* WT; int rows, cols, bc, br;
  if (bid < 2048 + 3072) {
    int tq = bid - 2048;
    W = W_qkv; WT = WqkvT; rows = 1024; cols = 3072;
    bc = (tq % 96) * 32; br = (tq / 96) * 32;
  } else {
    int tp = bid - 5120;
    W = W_proj; WT = WprojT; rows = 1024; cols = 1024;
    bc = (tp % 32) * 32; br = (tp / 32) * 32;
  }
  __shared__ float tile[32][33];
  int tx = threadIdx.x & 31, ty = threadIdx.x >> 5;
#pragma unroll
  for (int i = 0; i < 4; ++i)
    tile[ty + i * 8][tx] = W[(size_t)(br + ty + i * 8) * cols + bc + tx];
  __syncthreads();
#pragma unroll
  for (int i = 0; i < 4; ++i)
    WT[(size_t)(bc + ty + i * 8) * rows + br + tx] = f2bf(tile[tx][ty + i * 8]);
}

// ---------------- GEMM: C[M,N] = A[M,K=1024] * Bt[N,K=1024]^T ----------------
// 128xBN tile, BK=64, 256 threads (4 waves). Known-good single-buffer 2-barrier
// structure (R6-verified, thrice reproduced at ~41us for QKV).
// EPI 0 (QKV, grid 768): NEW 2D super-tile XCD map — each XCD covers 8mt x 12nt
// (L2 working set 5MB vs old 4mt x 24nt = 7MB > 4MB L2 -> B-panel thrash, the
// 2x FETCH over-fetch). Pure bijective index remap; inner loop untouched.
// EPI 1 (proj, BN=64, grid 512): R10-best mapping unchanged.
template <int EPI, int BN, int MINW>
__global__ __launch_bounds__(256, MINW) void gemm_bt(
    const unsigned short* __restrict__ A, const unsigned short* __restrict__ Bt,
    const float* __restrict__ bias, int NT,
    unsigned short* __restrict__ Oq, unsigned short* __restrict__ Ok,
    unsigned short* __restrict__ Ov, float* __restrict__ Of) {
  constexpr int WN = BN / 2;    // wave n-width
  constexpr int NI = BN / 32;   // 16-col fragments per wave
  constexpr int RB = BN / 32;   // B staging rounds (4KB each)
  __shared__ __align__(16) unsigned short lA[128 * 64];
  __shared__ __align__(16) unsigned short lB[BN * 64];

  int bid = blockIdx.x;
  int mt, nt;
  if (EPI == 0) {
    // 8 XCD regions of 8mt x 12nt over the 32 x 24 tile grid (bijective)
    int x = bid & 7, j = bid >> 3;              // x = XCD, j in [0,96)
    mt = (x >> 1) * 8 + j / 12;
    nt = (x & 1) * 12 + j % 12;
  } else {
    int cpx = gridDim.x >> 3;                   // grid % 8 == 0 (bijective XCD swizzle)
    int swz = (bid & 7) * cpx + (bid >> 3);
    mt = swz / NT; nt = swz % NT;
  }
  int m0 = mt * 128, n0 = nt * BN;

  int t = threadIdx.x, lane = t & 63, w = t >> 6;
  int wm = w >> 1, wn = w & 1;

  f32x4 acc[4][NI] = {};

  const char* gA = (const char*)(A + (size_t)m0 * 1024);
  const char* gB = (const char*)(Bt + (size_t)n0 * 1024);

  for (int kt = 0; kt < 16; ++kt) {
    __syncthreads();
#pragma unroll
    for (int r = 0; r < 4; ++r) {                 // A tile: 16KB
      int L = r * 4096 + t * 16;
      int row = L >> 7, cb = L & 127;
      int scb = cb ^ ((row & 7) << 4);
      gload16(gA + (size_t)row * 2048 + kt * 128 + scb, (char*)lA + (L - lane * 16));
    }
#pragma unroll
    for (int r = 0; r < RB; ++r) {                // B tile: BN*128 bytes
      int L = r * 4096 + t * 16;
      int row = L >> 7, cb = L & 127;
      int scb = cb ^ ((row & 7) << 4);
      gload16(gB + (size_t)row * 2048 + kt * 128 + scb, (char*)lB + (L - lane * 16));
    }
    __syncthreads();
#pragma unroll
    for (int kk = 0; kk < 2; ++kk) {
      bf16x8 af[4], bg[NI];
#pragma unroll
      for (int mi = 0; mi < 4; ++mi) {
        int row = wm * 64 + mi * 16 + (lane & 15);
        int byte = row * 128 + ((kk * 64 + (lane >> 4) * 16) ^ ((row & 7) << 4));
        af[mi] = *(const bf16x8*)((const char*)lA + byte);
      }
#pragma unroll
      for (int ni = 0; ni < NI; ++ni) {
        int row = wn * WN + ni * 16 + (lane & 15);
        int byte = row * 128 + ((kk * 64 + (lane >> 4) * 16) ^ ((row & 7) << 4));
        bg[ni] = *(const bf16x8*)((const char*)lB + byte);
      }
      __builtin_amdgcn_s_setprio(1);
#pragma unroll
      for (int mi = 0; mi < 4; ++mi)
#pragma unroll
        for (int ni = 0; ni < NI; ++ni)
          acc[mi][ni] = __builtin_amdgcn_mfma_f32_16x16x32_bf16(af[mi], bg[ni], acc[mi][ni], 0, 0, 0);
      __builtin_amdgcn_s_setprio(0);
    }
  }

  // epilogue: D row=(lane>>4)*4+r, col=lane&15 (m89-verified layout)
#pragma unroll
  for (int mi = 0; mi < 4; ++mi)
#pragma unroll
    for (int ni = 0; ni < NI; ++ni) {
      int col = n0 + wn * WN + ni * 16 + (lane & 15);
      float bv = bias[col];
#pragma unroll
      for (int r = 0; r < 4; ++r) {
        int row = m0 + wm * 64 + mi * 16 + (lane >> 4) * 4 + r;
        float v = acc[mi][ni][r] + bv;
        if (EPI == 0) {
          int which = col >> 10, dd = col & 1023;
          int h = dd >> 6, hd = dd & 63;
          int b = row >> 11, s = row & 2047;
          size_t bh = (size_t)(b * 16 + h);
          if (which == 0)      Oq[(bh * 2048 + s) * 64 + hd] = f2bf(v * SCALE_QL2);
          else if (which == 1) Ok[(bh * 2048 + s) * 64 + hd] = f2bf(v);
          else                 Ov[(bh * 64 + hd) * 2048 + s] = f2bf(v);
        } else {
          Of[(size_t)row * 1024 + col] = v;
        }
      }
    }
}

// ---------------- split-KV causal flash attention (4 waves, QBLK=128, chunk=8) ------
// R15/R17 configuration (session best, thrice reproduced): K+V staged LDS dbuf 32KB,
// counted vmcnt(4), heavy-first slots, XCD affinity, swapped-QK^T 32x32x16, in-reg
// softmax with broken dep chains (v_max3 tree + 4-way partial sums), T12, T13.
__global__ __launch_bounds__(256, 4) void attn_split(
    const unsigned short* __restrict__ Qb, const unsigned short* __restrict__ Kb,
    const unsigned short* __restrict__ Vt,
    unsigned short* __restrict__ PO, float* __restrict__ PML) {
  __shared__ __align__(16) unsigned short lK[2][64 * 64];
  __shared__ __align__(16) unsigned short lV[2][64 * 64];

  int id = blockIdx.x;
  int bh = id & 31;                 // id%8 == bh%8 -> XCD L2 affinity
  int slot = 39 - (id >> 5);        // heavy (a=3) slots dispatch first
  int a, g;
  if (slot < 4)       { a = 0; g = slot; }
  else if (slot < 12) { a = 1; g = slot - 4; }
  else if (slot < 24) { a = 2; g = slot - 12; }
  else                { a = 3; g = slot - 24; }
  int Tg = (a == 0) ? g : (a == 1) ? (g >> 1) : (a == 2) ? ((g * 11) >> 5) : (g >> 2);
  int T  = a * 4 + Tg;
  int c  = g - Tg * (a + 1);
  int t0 = c * 8;
  int tend = min(t0 + 7, 2 * T + 1);

  int t = threadIdx.x, lane = t & 63, w = t >> 6;   // w in {0,1,2,3}
  int lo = lane & 31, hi = lane >> 5;
  int q0w = T * 128 + w * 32;
  int itmaxw = 2 * T + (w >> 1);    // last kv-tile this wave's q-rows can see
  int swzb = (lo & 7) << 4;

  const unsigned short* Qg = Qb + ((size_t)bh * 2048 + q0w + lo) * 64 + hi * 8;
  bf16x8 qf[4];
#pragma unroll
  for (int kk = 0; kk < 4; ++kk) qf[kk] = *(const bf16x8*)(Qg + kk * 16);

  f32x16 o0 = {}, o1 = {};          // O[q=crow(r,hi)][d = 32*dh + lo]
  float m = -1e30f, lsum = 0.f;

  const char* Kg = (const char*)(Kb + (size_t)bh * 2048 * 64);
  const char* Vg = (const char*)(Vt + (size_t)bh * 64 * 2048);

  int Lb = t * 16;
  auto STAGE = [&](int buf, int tile) {
    int s0 = tile * 64;
#pragma unroll
    for (int r = 0; r < 2; ++r) {
      int L = r * 4096 + Lb;
      int row = L >> 7, cb = L & 127;
      int scb = cb ^ ((row & 7) << 4);
      gload16(Kg + (size_t)(s0 + row) * 128 + scb, (char*)&lK[buf][0] + (L - lane * 16));
      gload16(Vg + (size_t)row * 4096 + (size_t)s0 * 2 + scb, (char*)&lV[buf][0] + (L - lane * 16));
    }
  };

  STAGE(0, t0);

  int cur = 0;
  for (int it = t0; it <= tend; ++it) {
    if (it < tend) {
      STAGE(cur ^ 1, it + 1);
      asm volatile("s_waitcnt vmcnt(4)" ::: "memory");
    } else {
      asm volatile("s_waitcnt vmcnt(0)" ::: "memory");
    }
    asm volatile("s_barrier" ::: "memory");

    if (it <= itmaxw) {
      const char* bK = (const char*)&lK[cur][0];
      const char* bV = (const char*)&lV[cur][0];

      f32x16 sv0 = {}, sv1 = {};
      __builtin_amdgcn_s_setprio(1);
#pragma unroll
      for (int kk = 0; kk < 4; ++kk) {
        int dby = 32 * kk + 16 * hi;
        bf16x8 k0 = *(const bf16x8*)(bK + lo * 128 + (dby ^ swzb));
        bf16x8 k1 = *(const bf16x8*)(bK + (32 + lo) * 128 + (dby ^ swzb));
        sv0 = __builtin_amdgcn_mfma_f32_32x32x16_bf16(k0, qf[kk], sv0, 0, 0, 0);
        sv1 = __builtin_amdgcn_mfma_f32_32x32x16_bf16(k1, qf[kk], sv1, 0, 0, 0);
      }
      __builtin_amdgcn_s_setprio(0);

      if (it == itmaxw) {
        int qg2 = q0w + lo, s0 = it * 64;
#pragma unroll
        for (int r = 0; r < 16; ++r) {
          int kv = s0 + (r & 3) + 8 * (r >> 2) + 4 * hi;
          if (kv > qg2) sv0[r] = -1e30f;
          if (kv + 32 > qg2) sv1[r] = -1e30f;
        }
      }

      // row max: 4 independent v_max3 chains + combine
      float t0m = -1e30f, t1m = -1e30f, t2m = -1e30f, t3m = -1e30f;
#pragma unroll
      for (int r = 0; r < 16; r += 4) {
        t0m = max3f(t0m, sv0[r + 0], sv1[r + 0]);
        t1m = max3f(t1m, sv0[r + 1], sv1[r + 1]);
        t2m = max3f(t2m, sv0[r + 2], sv1[r + 2]);
        t3m = max3f(t3m, sv0[r + 3], sv1[r + 3]);
      }
      float rmax = fmaxf(fmaxf(t0m, t1m), fmaxf(t2m, t3m));
      rmax = fmaxf(rmax, __shfl_xor(rmax, 32));

      // T13 defer-max (exp2 domain, THR=8 -> p <= 256)
      if (__any(rmax > m + 8.0f)) {
        float mn = fmaxf(m, rmax);
        float sf = fexp2(m - mn);
        m = mn; lsum *= sf;
#pragma unroll
        for (int r = 0; r < 16; ++r) {
          float s = __shfl(sf, (r & 3) + 8 * (r >> 2) + 4 * hi);
          o0[r] *= s; o1[r] *= s;
        }
      }

      // p = 2^(s-m); row sum via 4 independent accumulators
      float rs0 = 0.f, rs1 = 0.f, rs2 = 0.f, rs3 = 0.f;
#pragma unroll
      for (int r = 0; r < 16; r += 2) {
        sv0[r]     = fexp2(sv0[r] - m);     rs0 += sv0[r];
        sv0[r + 1] = fexp2(sv0[r + 1] - m); rs1 += sv0[r + 1];
        sv1[r]     = fexp2(sv1[r] - m);     rs2 += sv1[r];
        sv1[r + 1] = fexp2(sv1[r + 1] - m); rs3 += sv1[r + 1];
      }
      float rsum = (rs0 + rs1) + (rs2 + rs3);
      rsum += __shfl_xor(rsum, 32);
      lsum += rsum;

      bf16x8 pa[4];
#pragma unroll
      for (int h2 = 0; h2 < 2; ++h2) {
        const f32x16& P = h2 ? sv1 : sv0;
#pragma unroll
        for (int kp = 0; kp < 2; ++kp) {
          unsigned a0 = cvtpk(P[8 * kp + 0], P[8 * kp + 1]);
          unsigned a1 = cvtpk(P[8 * kp + 2], P[8 * kp + 3]);
          unsigned b0 = cvtpk(P[8 * kp + 4], P[8 * kp + 5]);
          unsigned b1 = cvtpk(P[8 * kp + 6], P[8 * kp + 7]);
          plswap(a0, b0); plswap(a1, b1);
          union { unsigned u[4]; bf16x8 v; } uu;
          uu.u[0] = a0; uu.u[1] = a1; uu.u[2] = b0; uu.u[3] = b1;
          pa[2 * h2 + kp] = uu.v;
        }
      }

      __builtin_amdgcn_s_setprio(1);
#pragma unroll
      for (int dh = 0; dh < 2; ++dh) {
        f32x16& oc = dh ? o1 : o0;
#pragma unroll
        for (int ks = 0; ks < 4; ++ks) {
          int kvby = 32 * ks + 16 * hi;
          bf16x8 vf = *(const bf16x8*)(bV + (32 * dh + lo) * 128 + (kvby ^ swzb));
          oc = __builtin_amdgcn_mfma_f32_32x32x16_bf16(pa[ks], vf, oc, 0, 0, 0);
        }
      }
      __builtin_amdgcn_s_setprio(0);
    }

    asm volatile("s_barrier" ::: "memory");
    cur ^= 1;
  }

  size_t pobase = (size_t)(bh * 40 + slot) * 128;
#pragma unroll
  for (int r = 0; r < 16; ++r) {
    int crow = (r & 3) + 8 * (r >> 2) + 4 * hi;
    size_t rowoff = (pobase + w * 32 + crow) * 64 + lo;
    PO[rowoff]      = f2bf(o0[r]);
    PO[rowoff + 32] = f2bf(o1[r]);
  }
  if (hi == 0) {
    size_t mlbase = (size_t)(bh * 40 + slot) * 256 + w * 32 + lo;
    PML[mlbase]       = m;
    PML[mlbase + 128] = lsum;
  }
}

// ---------------- combine partials -> attn [B,S,D] bf16 ----------------
__global__ void attn_combine(const unsigned short* __restrict__ PO,
                             const float* __restrict__ PML,
                             unsigned short* __restrict__ attn) {
  int id = blockIdx.x * 256 + threadIdx.x;
  int dg = id & 7;
  int s  = (id >> 3) & 2047;
  int bh = id >> 14;
  int T = s >> 7, a = T >> 2;
  int nc = a + 1;
  int slot0 = (a + 1) * (T - 2 * a);
  int r128 = s & 127;
  int pb = bh * 40 + slot0;

  float mv[4], lv[4];
#pragma unroll
  for (int c = 0; c < 4; ++c) {
    if (c < nc) {
      mv[c] = PML[(size_t)(pb + c) * 256 + r128];
      lv[c] = PML[(size_t)(pb + c) * 256 + 128 + r128];
    } else { mv[c] = -1e30f; lv[c] = 0.f; }
  }
  float M = fmaxf(fmaxf(mv[0], mv[1]), fmaxf(mv[2], mv[3]));
  float wv[4], L = 0.f;
#pragma unroll
  for (int c = 0; c < 4; ++c) { wv[c] = fexp2(mv[c] - M); L += wv[c] * lv[c]; }
  float rcpL = 1.0f / L;

  float acc[8] = {};
#pragma unroll
  for (int c = 0; c < 4; ++c) {
    if (c < nc) {
      bf16x8 p = *(const bf16x8*)(PO + ((size_t)(pb + c) * 128 + r128) * 64 + dg * 8);
#pragma unroll
      for (int j = 0; j < 8; ++j) acc[j] += wv[c] * bf2f((unsigned short)p[j]);
    }
  }
  u16x8 o;
#pragma unroll
  for (int j = 0; j < 8; ++j) o[j] = f2bf(acc[j] * rcpL);
  int b = bh >> 4, h = bh & 15;
  *(u16x8*)(attn + ((size_t)(b * 2048 + s)) * 1024 + h * 64 + dg * 8) = o;
}

// ---------------- launcher ----------------
extern "C" void kernel_launch(void* const* d_in, const int* in_sizes, int n_in,
                              void* d_out, int out_size, void* d_ws, size_t ws_size,
                              hipStream_t stream) {
  const float* x      = (const float*)d_in[0];
  const float* W_qkv  = (const float*)d_in[1];
  const float* b_qkv  = (const float*)d_in[2];
  const float* W_proj = (const float*)d_in[3];
  const float* b_proj = (const float*)d_in[4];
  float* out = (float*)d_out;

  char* ws = (char*)d_ws;
  const size_t MB = 1u << 20;
  unsigned short* xb     = (unsigned short*)(ws);            // 8 MB (reused as attn out)
  unsigned short* WqkvT  = (unsigned short*)(ws + 8 * MB);   // 6 MB
  unsigned short* WprojT = (unsigned short*)(ws + 14 * MB);  // 2 MB
  unsigned short* Qb     = (unsigned short*)(ws + 16 * MB);  // 8 MB
  unsigned short* Kb     = (unsigned short*)(ws + 24 * MB);  // 8 MB
  unsigned short* Vt     = (unsigned short*)(ws + 32 * MB);  // 8 MB
  unsigned short* PO     = (unsigned short*)(ws + 40 * MB);  // 20 MB partial O (bf16)
  float*          PML    = (float*)(ws + 60 * MB);           // 1.31 MB partial (m,l)
  unsigned short* attn   = xb;                               // alias: xb dead after QKV GEMM

  prep<<<6144, 256, 0, stream>>>(x, xb, W_qkv, WqkvT, W_proj, WprojT);
  gemm_bt<0, 128, 2><<<768, 256, 0, stream>>>(xb, WqkvT, b_qkv, 24, Qb, Kb, Vt, nullptr);
  attn_split<<<1280, 256, 0, stream>>>(Qb, Kb, Vt, PO, PML);
  attn_combine<<<2048, 256, 0, stream>>>(PO, PML, attn);
  gemm_bt<1, 64, 5><<<512, 256, 0, stream>>>(attn, WprojT, b_proj, 16, nullptr, nullptr, nullptr, out);
}

// Round 21
// 113.514 us; speedup vs baseline: 1.0360x; 1.0360x over previous
//
#include <hip/hip_runtime.h>
#include <stdint.h>

// Problem constants
#define NB 2
#define NS 2048
#define ND 1024
#define NH 16
#define NHD 64
#define SCALE_QL2 0.1803368801111244f  // (1/sqrt(64)) * log2(e): attention runs in exp2 domain

typedef __attribute__((ext_vector_type(8))) short bf16x8;
typedef __attribute__((ext_vector_type(4))) float f32x4;
typedef __attribute__((ext_vector_type(16))) float f32x16;
typedef __attribute__((ext_vector_type(8))) unsigned short u16x8;

__device__ __forceinline__ unsigned short f2bf(float f) {
  union { float f; unsigned u; } v; v.f = f;
  unsigned r = v.u + 0x7FFFu + ((v.u >> 16) & 1u);
  return (unsigned short)(r >> 16);
}

__device__ __forceinline__ float bf2f(unsigned short u) {
  union { unsigned u; float f; } v; v.u = ((unsigned)u) << 16;
  return v.f;
}

__device__ __forceinline__ float fexp2(float x) { return __builtin_amdgcn_exp2f(x); }

// 3-input max, single VALU op (gfx9+); T17
__device__ __forceinline__ float max3f(float a, float b, float c) {
  float r;
  asm("v_max3_f32 %0, %1, %2, %3" : "=v"(r) : "v"(a), "v"(b), "v"(c));
  return r;
}

// pack 2 f32 -> 1 u32 of 2 bf16 (lo = a, hi = b), RNE
__device__ __forceinline__ unsigned cvtpk(float a, float b) {
  unsigned r;
  asm("v_cvt_pk_bf16_f32 %0, %1, %2" : "=v"(r) : "v"(a), "v"(b));
  return r;
}

// cross-half exchange: a' = [a_lo32lanes, b_lo32lanes], b' = [a_hi32lanes, b_hi32lanes]
__device__ __forceinline__ void plswap(unsigned& a, unsigned& b) {
  asm("v_permlane32_swap_b32 %0, %1" : "+v"(a), "+v"(b));
}

// async global->LDS, 16B per lane. Dest must be wave-uniform base (HW adds lane*16).
__device__ __forceinline__ void gload16(const void* g, void* l) {
  __builtin_amdgcn_global_load_lds(
      (const __attribute__((address_space(1))) unsigned int*)g,
      (__attribute__((address_space(3))) unsigned int*)l, 16, 0, 0);
}

// ---------------- merged prep kernel (cvt_x + both weight transposes) ----------------
__global__ void prep(const float* __restrict__ x, unsigned short* __restrict__ xb,
                     const float* __restrict__ W_qkv, unsigned short* __restrict__ WqkvT,
                     const float* __restrict__ W_proj, unsigned short* __restrict__ WprojT) {
  int bid = blockIdx.x;
  if (bid < 2048) {
    int i = bid * 256 + threadIdx.x;
    const float4* p = (const float4*)x + (size_t)i * 2;
    float4 a = p[0], b = p[1];
    u16x8 o;
    o[0] = f2bf(a.x); o[1] = f2bf(a.y); o[2] = f2bf(a.z); o[3] = f2bf(a.w);
    o[4] = f2bf(b.x); o[5] = f2bf(b.y); o[6] = f2bf(b.z); o[7] = f2bf(b.w);
    *((u16x8*)xb + i) = o;
    return;
  }
  const float* W; unsigned short* WT; int rows, cols, bc, br;
  if (bid < 2048 + 3072) {
    int tq = bid - 2048;
    W = W_qkv; WT = WqkvT; rows = 1024; cols = 3072;
    bc = (tq % 96) * 32; br = (tq / 96) * 32;
  } else {
    int tp = bid - 5120;
    W = W_proj; WT = WprojT; rows = 1024; cols = 1024;
    bc = (tp % 32) * 32; br = (tp / 32) * 32;
  }
  __shared__ float tile[32][33];
  int tx = threadIdx.x & 31, ty = threadIdx.x >> 5;
#pragma unroll
  for (int i = 0; i < 4; ++i)
    tile[ty + i * 8][tx] = W[(size_t)(br + ty + i * 8) * cols + bc + tx];
  __syncthreads();
#pragma unroll
  for (int i = 0; i < 4; ++i)
    WT[(size_t)(bc + ty + i * 8) * rows + br + tx] = f2bf(tile[tx][ty + i * 8]);
}

// ---------------- GEMM: C[M,N] = A[M,K=1024] * Bt[N,K=1024]^T ----------------
// 128xBN tile, BK=64, 256 threads (4 waves). Known-good single-buffer 2-barrier
// structure. BN=128/MINW=2 for QKV — best of all measured variants
// {8-phase:76, dbuf:57, 128x64:49, 8-wave:54, 2D-XCD-map:46, this:~41us}.
// BN=64/MINW=5 for proj (2 blocks/CU — R10 evidence).
template <int EPI, int BN, int MINW>
__global__ __launch_bounds__(256, MINW) void gemm_bt(
    const unsigned short* __restrict__ A, const unsigned short* __restrict__ Bt,
    const float* __restrict__ bias, int NT,
    unsigned short* __restrict__ Oq, unsigned short* __restrict__ Ok,
    unsigned short* __restrict__ Ov, float* __restrict__ Of) {
  constexpr int WN = BN / 2;    // wave n-width
  constexpr int NI = BN / 32;   // 16-col fragments per wave
  constexpr int RB = BN / 32;   // B staging rounds (4KB each)
  __shared__ __align__(16) unsigned short lA[128 * 64];
  __shared__ __align__(16) unsigned short lB[BN * 64];

  int bid = blockIdx.x;
  int cpx = gridDim.x >> 3;                       // grid % 8 == 0 (bijective XCD swizzle)
  int swz = (bid & 7) * cpx + (bid >> 3);
  int mt = swz / NT, nt = swz % NT;
  int m0 = mt * 128, n0 = nt * BN;

  int t = threadIdx.x, lane = t & 63, w = t >> 6;
  int wm = w >> 1, wn = w & 1;

  f32x4 acc[4][NI] = {};

  const char* gA = (const char*)(A + (size_t)m0 * 1024);
  const char* gB = (const char*)(Bt + (size_t)n0 * 1024);

  for (int kt = 0; kt < 16; ++kt) {
    __syncthreads();
#pragma unroll
    for (int r = 0; r < 4; ++r) {                 // A tile: 16KB
      int L = r * 4096 + t * 16;
      int row = L >> 7, cb = L & 127;
      int scb = cb ^ ((row & 7) << 4);
      gload16(gA + (size_t)row * 2048 + kt * 128 + scb, (char*)lA + (L - lane * 16));
    }
#pragma unroll
    for (int r = 0; r < RB; ++r) {                // B tile: BN*128 bytes
      int L = r * 4096 + t * 16;
      int row = L >> 7, cb = L & 127;
      int scb = cb ^ ((row & 7) << 4);
      gload16(gB + (size_t)row * 2048 + kt * 128 + scb, (char*)lB + (L - lane * 16));
    }
    __syncthreads();
#pragma unroll
    for (int kk = 0; kk < 2; ++kk) {
      bf16x8 af[4], bg[NI];
#pragma unroll
      for (int mi = 0; mi < 4; ++mi) {
        int row = wm * 64 + mi * 16 + (lane & 15);
        int byte = row * 128 + ((kk * 64 + (lane >> 4) * 16) ^ ((row & 7) << 4));
        af[mi] = *(const bf16x8*)((const char*)lA + byte);
      }
#pragma unroll
      for (int ni = 0; ni < NI; ++ni) {
        int row = wn * WN + ni * 16 + (lane & 15);
        int byte = row * 128 + ((kk * 64 + (lane >> 4) * 16) ^ ((row & 7) << 4));
        bg[ni] = *(const bf16x8*)((const char*)lB + byte);
      }
      __builtin_amdgcn_s_setprio(1);
#pragma unroll
      for (int mi = 0; mi < 4; ++mi)
#pragma unroll
        for (int ni = 0; ni < NI; ++ni)
          acc[mi][ni] = __builtin_amdgcn_mfma_f32_16x16x32_bf16(af[mi], bg[ni], acc[mi][ni], 0, 0, 0);
      __builtin_amdgcn_s_setprio(0);
    }
  }

  // epilogue: D row=(lane>>4)*4+r, col=lane&15 (m89-verified layout)
#pragma unroll
  for (int mi = 0; mi < 4; ++mi)
#pragma unroll
    for (int ni = 0; ni < NI; ++ni) {
      int col = n0 + wn * WN + ni * 16 + (lane & 15);
      float bv = bias[col];
#pragma unroll
      for (int r = 0; r < 4; ++r) {
        int row = m0 + wm * 64 + mi * 16 + (lane >> 4) * 4 + r;
        float v = acc[mi][ni][r] + bv;
        if (EPI == 0) {
          int which = col >> 10, dd = col & 1023;
          int h = dd >> 6, hd = dd & 63;
          int b = row >> 11, s = row & 2047;
          size_t bh = (size_t)(b * 16 + h);
          if (which == 0)      Oq[(bh * 2048 + s) * 64 + hd] = f2bf(v * SCALE_QL2);
          else if (which == 1) Ok[(bh * 2048 + s) * 64 + hd] = f2bf(v);
          else                 Ov[(bh * 64 + hd) * 2048 + s] = f2bf(v);
        } else {
          Of[(size_t)row * 1024 + col] = v;
        }
      }
    }
}

// ---------------- split-KV causal flash attention (4 waves, QBLK=128, chunk=8) ------
// Session-best configuration (reproduced at 113.6/113.7/113.8us): K+V staged LDS
// dbuf 32KB, counted vmcnt(4), heavy-first slots, XCD affinity, swapped-QK^T
// 32x32x16, in-reg softmax with broken dep chains (v_max3 tree + 4-way partial
// sums), T12 cvt_pk+permlane, T13 defer-max.
__global__ __launch_bounds__(256, 4) void attn_split(
    const unsigned short* __restrict__ Qb, const unsigned short* __restrict__ Kb,
    const unsigned short* __restrict__ Vt,
    unsigned short* __restrict__ PO, float* __restrict__ PML) {
  __shared__ __align__(16) unsigned short lK[2][64 * 64];
  __shared__ __align__(16) unsigned short lV[2][64 * 64];

  int id = blockIdx.x;
  int bh = id & 31;                 // id%8 == bh%8 -> XCD L2 affinity
  int slot = 39 - (id >> 5);        // heavy (a=3) slots dispatch first
  int a, g;
  if (slot < 4)       { a = 0; g = slot; }
  else if (slot < 12) { a = 1; g = slot - 4; }
  else if (slot < 24) { a = 2; g = slot - 12; }
  else                { a = 3; g = slot - 24; }
  int Tg = (a == 0) ? g : (a == 1) ? (g >> 1) : (a == 2) ? ((g * 11) >> 5) : (g >> 2);
  int T  = a * 4 + Tg;
  int c  = g - Tg * (a + 1);
  int t0 = c * 8;
  int tend = min(t0 + 7, 2 * T + 1);

  int t = threadIdx.x, lane = t & 63, w = t >> 6;   // w in {0,1,2,3}
  int lo = lane & 31, hi = lane >> 5;
  int q0w = T * 128 + w * 32;
  int itmaxw = 2 * T + (w >> 1);    // last kv-tile this wave's q-rows can see
  int swzb = (lo & 7) << 4;

  const unsigned short* Qg = Qb + ((size_t)bh * 2048 + q0w + lo) * 64 + hi * 8;
  bf16x8 qf[4];
#pragma unroll
  for (int kk = 0; kk < 4; ++kk) qf[kk] = *(const bf16x8*)(Qg + kk * 16);

  f32x16 o0 = {}, o1 = {};          // O[q=crow(r,hi)][d = 32*dh + lo]
  float m = -1e30f, lsum = 0.f;

  const char* Kg = (const char*)(Kb + (size_t)bh * 2048 * 64);
  const char* Vg = (const char*)(Vt + (size_t)bh * 64 * 2048);

  int Lb = t * 16;
  auto STAGE = [&](int buf, int tile) {
    int s0 = tile * 64;
#pragma unroll
    for (int r = 0; r < 2; ++r) {
      int L = r * 4096 + Lb;
      int row = L >> 7, cb = L & 127;
      int scb = cb ^ ((row & 7) << 4);
      gload16(Kg + (size_t)(s0 + row) * 128 + scb, (char*)&lK[buf][0] + (L - lane * 16));
      gload16(Vg + (size_t)row * 4096 + (size_t)s0 * 2 + scb, (char*)&lV[buf][0] + (L - lane * 16));
    }
  };

  STAGE(0, t0);

  int cur = 0;
  for (int it = t0; it <= tend; ++it) {
    if (it < tend) {
      STAGE(cur ^ 1, it + 1);
      asm volatile("s_waitcnt vmcnt(4)" ::: "memory");
    } else {
      asm volatile("s_waitcnt vmcnt(0)" ::: "memory");
    }
    asm volatile("s_barrier" ::: "memory");

    if (it <= itmaxw) {
      const char* bK = (const char*)&lK[cur][0];
      const char* bV = (const char*)&lV[cur][0];

      f32x16 sv0 = {}, sv1 = {};
      __builtin_amdgcn_s_setprio(1);
#pragma unroll
      for (int kk = 0; kk < 4; ++kk) {
        int dby = 32 * kk + 16 * hi;
        bf16x8 k0 = *(const bf16x8*)(bK + lo * 128 + (dby ^ swzb));
        bf16x8 k1 = *(const bf16x8*)(bK + (32 + lo) * 128 + (dby ^ swzb));
        sv0 = __builtin_amdgcn_mfma_f32_32x32x16_bf16(k0, qf[kk], sv0, 0, 0, 0);
        sv1 = __builtin_amdgcn_mfma_f32_32x32x16_bf16(k1, qf[kk], sv1, 0, 0, 0);
      }
      __builtin_amdgcn_s_setprio(0);

      if (it == itmaxw) {
        int qg2 = q0w + lo, s0 = it * 64;
#pragma unroll
        for (int r = 0; r < 16; ++r) {
          int kv = s0 + (r & 3) + 8 * (r >> 2) + 4 * hi;
          if (kv > qg2) sv0[r] = -1e30f;
          if (kv + 32 > qg2) sv1[r] = -1e30f;
        }
      }

      // row max: 4 independent v_max3 chains + combine
      float t0m = -1e30f, t1m = -1e30f, t2m = -1e30f, t3m = -1e30f;
#pragma unroll
      for (int r = 0; r < 16; r += 4) {
        t0m = max3f(t0m, sv0[r + 0], sv1[r + 0]);
        t1m = max3f(t1m, sv0[r + 1], sv1[r + 1]);
        t2m = max3f(t2m, sv0[r + 2], sv1[r + 2]);
        t3m = max3f(t3m, sv0[r + 3], sv1[r + 3]);
      }
      float rmax = fmaxf(fmaxf(t0m, t1m), fmaxf(t2m, t3m));
      rmax = fmaxf(rmax, __shfl_xor(rmax, 32));

      // T13 defer-max (exp2 domain, THR=8 -> p <= 256)
      if (__any(rmax > m + 8.0f)) {
        float mn = fmaxf(m, rmax);
        float sf = fexp2(m - mn);
        m = mn; lsum *= sf;
#pragma unroll
        for (int r = 0; r < 16; ++r) {
          float s = __shfl(sf, (r & 3) + 8 * (r >> 2) + 4 * hi);
          o0[r] *= s; o1[r] *= s;
        }
      }

      // p = 2^(s-m); row sum via 4 independent accumulators
      float rs0 = 0.f, rs1 = 0.f, rs2 = 0.f, rs3 = 0.f;
#pragma unroll
      for (int r = 0; r < 16; r += 2) {
        sv0[r]     = fexp2(sv0[r] - m);     rs0 += sv0[r];
        sv0[r + 1] = fexp2(sv0[r + 1] - m); rs1 += sv0[r + 1];
        sv1[r]     = fexp2(sv1[r] - m);     rs2 += sv1[r];
        sv1[r + 1] = fexp2(sv1[r + 1] - m); rs3 += sv1[r + 1];
      }
      float rsum = (rs0 + rs1) + (rs2 + rs3);
      rsum += __shfl_xor(rsum, 32);
      lsum += rsum;

      bf16x8 pa[4];
#pragma unroll
      for (int h2 = 0; h2 < 2; ++h2) {
        const f32x16& P = h2 ? sv1 : sv0;
#pragma unroll
        for (int kp = 0; kp < 2; ++kp) {
          unsigned a0 = cvtpk(P[8 * kp + 0], P[8 * kp + 1]);
          unsigned a1 = cvtpk(P[8 * kp + 2], P[8 * kp + 3]);
          unsigned b0 = cvtpk(P[8 * kp + 4], P[8 * kp + 5]);
          unsigned b1 = cvtpk(P[8 * kp + 6], P[8 * kp + 7]);
          plswap(a0, b0); plswap(a1, b1);
          union { unsigned u[4]; bf16x8 v; } uu;
          uu.u[0] = a0; uu.u[1] = a1; uu.u[2] = b0; uu.u[3] = b1;
          pa[2 * h2 + kp] = uu.v;
        }
      }

      __builtin_amdgcn_s_setprio(1);
#pragma unroll
      for (int dh = 0; dh < 2; ++dh) {
        f32x16& oc = dh ? o1 : o0;
#pragma unroll
        for (int ks = 0; ks < 4; ++ks) {
          int kvby = 32 * ks + 16 * hi;
          bf16x8 vf = *(const bf16x8*)(bV + (32 * dh + lo) * 128 + (kvby ^ swzb));
          oc = __builtin_amdgcn_mfma_f32_32x32x16_bf16(pa[ks], vf, oc, 0, 0, 0);
        }
      }
      __builtin_amdgcn_s_setprio(0);
    }

    asm volatile("s_barrier" ::: "memory");
    cur ^= 1;
  }

  size_t pobase = (size_t)(bh * 40 + slot) * 128;
#pragma unroll
  for (int r = 0; r < 16; ++r) {
    int crow = (r & 3) + 8 * (r >> 2) + 4 * hi;
    size_t rowoff = (pobase + w * 32 + crow) * 64 + lo;
    PO[rowoff]      = f2bf(o0[r]);
    PO[rowoff + 32] = f2bf(o1[r]);
  }
  if (hi == 0) {
    size_t mlbase = (size_t)(bh * 40 + slot) * 256 + w * 32 + lo;
    PML[mlbase]       = m;
    PML[mlbase + 128] = lsum;
  }
}

// ---------------- combine partials -> attn [B,S,D] bf16 ----------------
__global__ void attn_combine(const unsigned short* __restrict__ PO,
                             const float* __restrict__ PML,
                             unsigned short* __restrict__ attn) {
  int id = blockIdx.x * 256 + threadIdx.x;
  int dg = id & 7;
  int s  = (id >> 3) & 2047;
  int bh = id >> 14;
  int T = s >> 7, a = T >> 2;
  int nc = a + 1;
  int slot0 = (a + 1) * (T - 2 * a);
  int r128 = s & 127;
  int pb = bh * 40 + slot0;

  float mv[4], lv[4];
#pragma unroll
  for (int c = 0; c < 4; ++c) {
    if (c < nc) {
      mv[c] = PML[(size_t)(pb + c) * 256 + r128];
      lv[c] = PML[(size_t)(pb + c) * 256 + 128 + r128];
    } else { mv[c] = -1e30f; lv[c] = 0.f; }
  }
  float M = fmaxf(fmaxf(mv[0], mv[1]), fmaxf(mv[2], mv[3]));
  float wv[4], L = 0.f;
#pragma unroll
  for (int c = 0; c < 4; ++c) { wv[c] = fexp2(mv[c] - M); L += wv[c] * lv[c]; }
  float rcpL = 1.0f / L;

  float acc[8] = {};
#pragma unroll
  for (int c = 0; c < 4; ++c) {
    if (c < nc) {
      bf16x8 p = *(const bf16x8*)(PO + ((size_t)(pb + c) * 128 + r128) * 64 + dg * 8);
#pragma unroll
      for (int j = 0; j < 8; ++j) acc[j] += wv[c] * bf2f((unsigned short)p[j]);
    }
  }
  u16x8 o;
#pragma unroll
  for (int j = 0; j < 8; ++j) o[j] = f2bf(acc[j] * rcpL);
  int b = bh >> 4, h = bh & 15;
  *(u16x8*)(attn + ((size_t)(b * 2048 + s)) * 1024 + h * 64 + dg * 8) = o;
}

// ---------------- launcher ----------------
extern "C" void kernel_launch(void* const* d_in, const int* in_sizes, int n_in,
                              void* d_out, int out_size, void* d_ws, size_t ws_size,
                              hipStream_t stream) {
  const float* x      = (const float*)d_in[0];
  const float* W_qkv  = (const float*)d_in[1];
  const float* b_qkv  = (const float*)d_in[2];
  const float* W_proj = (const float*)d_in[3];
  const float* b_proj = (const float*)d_in[4];
  float* out = (float*)d_out;

  char* ws = (char*)d_ws;
  const size_t MB = 1u << 20;
  unsigned short* xb     = (unsigned short*)(ws);            // 8 MB (reused as attn out)
  unsigned short* WqkvT  = (unsigned short*)(ws + 8 * MB);   // 6 MB
  unsigned short* WprojT = (unsigned short*)(ws + 14 * MB);  // 2 MB
  unsigned short* Qb     = (unsigned short*)(ws + 16 * MB);  // 8 MB
  unsigned short* Kb     = (unsigned short*)(ws + 24 * MB);  // 8 MB
  unsigned short* Vt     = (unsigned short*)(ws + 32 * MB);  // 8 MB
  unsigned short* PO     = (unsigned short*)(ws + 40 * MB);  // 20 MB partial O (bf16)
  float*          PML    = (float*)(ws + 60 * MB);           // 1.31 MB partial (m,l)
  unsigned short* attn   = xb;                               // alias: xb dead after QKV GEMM

  prep<<<6144, 256, 0, stream>>>(x, xb, W_qkv, WqkvT, W_proj, WprojT);
  gemm_bt<0, 128, 2><<<768, 256, 0, stream>>>(xb, WqkvT, b_qkv, 24, Qb, Kb, Vt, nullptr);
  attn_split<<<1280, 256, 0, stream>>>(Qb, Kb, Vt, PO, PML);
  attn_combine<<<2048, 256, 0, stream>>>(PO, PML, attn);
  gemm_bt<1, 64, 5><<<512, 256, 0, stream>>>(attn, WprojT, b_proj, 16, nullptr, nullptr, nullptr, out);
}